// Round 5
// baseline (25.166 us; speedup 1.0000x reference)
//
#include <hip/hip_runtime.h>
#include <math.h>

// Problem constants (from reference setup): B=4, N=65536, M=128.
#define NPTS 65536
#define MBOX 128
#define TPB  256

typedef float f32x16 __attribute__((ext_vector_type(16)));

// Atomic load+wait: both s_load_dwordx16 AND the lgkmcnt(0) wait live in ONE
// asm statement, so the SGPR outputs are genuinely valid when the asm
// retires. (R4's split issue/wait pattern let regalloc insert SGPR copies
// between issue and wait -> copied in-flight registers -> garbage. This
// pattern has no such window.)
#define SLOADCHUNK(q0, q1, base) \
    asm volatile("s_load_dwordx16 %0, %2, 0x0\n\t" \
                 "s_load_dwordx16 %1, %2, 0x40\n\t" \
                 "s_waitcnt lgkmcnt(0)" \
                 : "=&s"(q0), "=&s"(q1) : "s"(base) : "memory")

// Prep: per-box record {cx,cy,cz,hx,hy,hz,cos,sin} -> d_ws (global), so the
// main kernel can s_load it. Cross-kernel dataflow through d_ws is coherent
// (end-of-kernel release flushes L2; proven by R1/R2). Accurate sinf/cosf
// matches numpy (absmax=0.0 in R1-R3).
__global__ __launch_bounds__(256) void prep_boxes(const float* __restrict__ boxes,
                                                  float* __restrict__ prep,
                                                  int total) {
    int i = blockIdx.x * 256 + threadIdx.x;
    if (i >= total) return;
    const float* bx = boxes + (size_t)i * 7;
    float rz = bx[6];
    float* o = prep + (size_t)i * 8;
    o[0] = bx[0];          // cx
    o[1] = bx[1];          // cy
    o[2] = bx[2];          // cz
    o[3] = 0.5f * bx[3];   // hx (exact, matches ref dims*0.5)
    o[4] = 0.5f * bx[4];   // hy
    o[5] = 0.5f * bx[5];   // hz
    o[6] = cosf(rz);
    o[7] = sinf(rz);
}

// Main: 1 point/thread, 1024 blocks -> 4 blocks/CU, 16 waves/CU.
// Box records arrive via the SMEM pipe into SGPRs (4 boxes per fused
// load+wait chunk); every VALU op reads <=1 SGPR constant, so box data costs
// zero vector-pipe resources. K$-hit wait (~50cy) per chunk hides behind
// other waves' VALU (2.6x oversubscribed per SIMD).
// Descending m + overwrite: last write at smallest m == first containing box
// (matches reference argmax-first semantics).
// __f*_rn blocks fp-contract so rounding matches np (mul, mul, add — no fma).
__global__ __launch_bounds__(256) void pib_main(const float* __restrict__ points,
                                                const float* __restrict__ prep,
                                                float* __restrict__ out) {
    int b  = blockIdx.x >> 8;                     // 256 blocks per batch
    int pi = ((blockIdx.x & 255) << 8) + threadIdx.x;
    size_t gid = (size_t)b * NPTS + pi;

    const float* p = points + gid * 3;
    float px = p[0], py = p[1], pz = p[2];

    const float* bb = prep + (size_t)b * (MBOX * 8);

    int idx = -1;

    // Test one box whose record sits at q[off..off+7]; off is a literal 0/8
    // at each call site -> constant vector extracts, no scratch (rule #20).
    auto test1 = [&](const f32x16& q, int off, int m) {
        float cx = q[off + 0], cy = q[off + 1], cz = q[off + 2], hx = q[off + 3];
        float hy = q[off + 4], hz = q[off + 5], cr = q[off + 6], sr = q[off + 7];
        float lx = __fsub_rn(px, cx);
        float ly = __fsub_rn(py, cy);
        float lz = __fsub_rn(pz, cz);
        float X = __fadd_rn(__fmul_rn(lx, cr), __fmul_rn(ly, sr));
        // ref: -lx*sr + ly*cr ; fadd_rn(-a, b) == fsub_rn(b, a) exactly.
        float Y = __fsub_rn(__fmul_rn(ly, cr), __fmul_rn(lx, sr));
        bool in = (fabsf(X) <= hx) & (fabsf(Y) <= hy) & (fabsf(lz) <= hz);
        idx = in ? m : idx;
    };

    for (int c = MBOX / 4 - 1; c >= 0; --c) {     // chunks of 4 boxes, descending
        f32x16 q0, q1;
        SLOADCHUNK(q0, q1, bb + c * 32);
        test1(q1, 8, c * 4 + 3);                  // descending within chunk
        test1(q1, 0, c * 4 + 2);
        test1(q0, 8, c * 4 + 1);
        test1(q0, 0, c * 4 + 0);
    }

    out[gid] = (float)idx;                        // coalesced dword store
}

extern "C" void kernel_launch(void* const* d_in, const int* in_sizes, int n_in,
                              void* d_out, int out_size, void* d_ws, size_t ws_size,
                              hipStream_t stream) {
    const float* points = (const float*)d_in[0];   // [B, N, 3] f32
    const float* boxes  = (const float*)d_in[1];   // [B, M, 7] f32
    float* out = (float*)d_out;                    // [B, N]    f32
    float* prep = (float*)d_ws;                    // [B*M, 8]  f32 = 16 KB

    int n_points = in_sizes[0] / 3;                // B*N = 262144
    int n_boxes  = in_sizes[1] / 7;                // B*M = 512

    int prep_blocks = (n_boxes + 255) / 256;       // 2
    prep_boxes<<<prep_blocks, 256, 0, stream>>>(boxes, prep, n_boxes);

    int main_blocks = n_points / 256;              // 1024
    pib_main<<<main_blocks, 256, 0, stream>>>(points, prep, out);
}